// Round 2
// baseline (162.078 us; speedup 1.0000x reference)
//
#include <hip/hip_runtime.h>
#include <hip/hip_bf16.h>

// TriplesDistances: B=16, N=512, A=1024
// positions: float32 [B,N,3]; neighbors_j/k: int32 [B,N,A]; out: float32,
// (r_ij | r_ik | r_jk) each [B,N,A] concatenated flat.
//
// R7 post-mortem: phase-split (MLP=8) + (256,4) gave -5.5us (kernel ~44.5us
// vs ~27-30us traffic roofline). Partial win -> latency was a secondary
// factor. Remaining theory: float4 spos gather = ds_read_b128 whose bank
// group is idx%8 -> only 8 groups for 64 random lanes -> ~8-11-way
// serialization (~40cyc/gather, ~18us/CU of LDS time on the dependence
// chain).
// R8: split LDS layout: sxy float2[512] (b64, bank group idx%16, ~4-way ->
// 1.58x) + sz float[512] (b32, bank idx%32, ~2-way -> free). Cuts LDS gather
// time ~2.5x and LDS bytes 25%. Everything else unchanged.

namespace {
constexpr int kB = 16;
constexpr int kN = 512;
constexpr int kA = 1024;
constexpr long long kBNA = (long long)kB * kN * kA;  // 8,388,608

typedef int   iv4 __attribute__((ext_vector_type(4)));
typedef float fv4 __attribute__((ext_vector_type(4)));
}  // namespace

__global__ __launch_bounds__(256, 4) void TriplesDistances_kernel(
    const float* __restrict__ pos,   // f32 [B*N*3]
    const int* __restrict__ nj,      // int32 [B*N*A]
    const int* __restrict__ nk,      // int32 [B*N*A]
    float* __restrict__ out)         // f32 [3*B*N*A]
{
    __shared__ float2 sxy[kN];  // 4 KB: x,y of this batch's positions
    __shared__ float  sz[kN];   // 2 KB: z

    const int bid = blockIdx.x;        // 0..2047
    const int b   = bid >> 7;          // batch (128 blocks per batch)
    const int n0  = (bid & 127) << 2;  // first of 4 rows
    const int tid = threadIdx.x;

    // Stage batch-b positions: 1536 packed floats -> split xy/z layout.
    // Coalesced dword loads; scatter into sxy/sz (one-time, tiny).
    {
        const float* p = pos + (size_t)b * (kN * 3);
#pragma unroll
        for (int t = 0; t < 6; ++t) {
            const int e = tid + t * 256;
            const int a = e / 3;         // magic-mul, no HW div
            const int c = e - a * 3;
            const float v = p[e];
            if (c == 2) sz[a] = v;
            else ((float*)&sxy[a])[c] = v;
        }
    }

    const int wave = tid >> 6;          // 0..3 -> row n0+wave
    const int lane = tid & 63;
    const int row  = n0 + wave;

    // Wave owns the full 1024-element row; 4 chunks of 256 elements.
    // Thread offset lane*4 => every iv4 load / fv4 store is 1 KB coalesced.
    const long long rowbase = ((long long)b * kN + row) * kA;

    // ---- Phase 1: issue all 8 index loads; keep them ALL in flight. ----
    iv4 j4[4], k4[4];
#pragma unroll
    for (int c = 0; c < 4; ++c) {
        const long long off = rowbase + c * 256 + lane * 4;
        j4[c] = *(const iv4*)(nj + off);
        k4[c] = *(const iv4*)(nk + off);
    }

    __syncthreads();                    // spos ready (placed after load issue)
    const float2 xyi = sxy[row];
    const float xi = xyi.x, yi = xyi.y, zi = sz[row];

    // ---- Phase 2: per chunk, batch gathers -> compute -> store. ----
#pragma unroll
    for (int c = 0; c < 4; ++c) {
        const long long off = rowbase + c * 256 + lane * 4;

        const int js[4] = {j4[c].x, j4[c].y, j4[c].z, j4[c].w};
        const int ks[4] = {k4[c].x, k4[c].y, k4[c].z, k4[c].w};

        // Batch all gathers before any compute: 8x ds_read_b64 (~4-way)
        // + 8x ds_read_b32 (~2-way, free).
        float2 xyj[4], xyk[4];
        float  zj[4],  zk[4];
#pragma unroll
        for (int t = 0; t < 4; ++t) {
            xyj[t] = sxy[js[t]];
            zj[t]  = sz[js[t]];
            xyk[t] = sxy[ks[t]];
            zk[t]  = sz[ks[t]];
        }

        fv4 vij, vik, vjk;
        float* rij = (float*)&vij;
        float* rik = (float*)&vik;
        float* rjk = (float*)&vjk;
#pragma unroll
        for (int t = 0; t < 4; ++t) {
            // safe_norm: sqrtf(0)=0 matches where(s>0, sqrt(s), 0)
            float dx = xyj[t].x - xi, dy = xyj[t].y - yi, dz = zj[t] - zi;
            rij[t] = sqrtf(dx * dx + dy * dy + dz * dz);

            dx = xyk[t].x - xi; dy = xyk[t].y - yi; dz = zk[t] - zi;
            rik[t] = sqrtf(dx * dx + dy * dy + dz * dz);

            dx = xyj[t].x - xyk[t].x; dy = xyj[t].y - xyk[t].y; dz = zj[t] - zk[t];
            rjk[t] = sqrtf(dx * dx + dy * dy + dz * dz);
        }

        // 1 KB coalesced plain stores (overwrite poison-dirty L2 lines).
        *(fv4*)(out + off)            = vij;
        *(fv4*)(out + kBNA + off)     = vik;
        *(fv4*)(out + 2 * kBNA + off) = vjk;
    }
}

extern "C" void kernel_launch(void* const* d_in, const int* in_sizes, int n_in,
                              void* d_out, int out_size, void* d_ws, size_t ws_size,
                              hipStream_t stream) {
    const float* pos = (const float*)d_in[0];
    const int* nj = (const int*)d_in[1];
    const int* nk = (const int*)d_in[2];
    float* out = (float*)d_out;

    // 4 rows per block (1 per wave): grid = B * N/4 = 2048 blocks, 256 threads.
    TriplesDistances_kernel<<<kB * (kN / 4), 256, 0, stream>>>(pos, nj, nk, out);
}

// Round 3
// 154.580 us; speedup vs baseline: 1.0485x; 1.0485x over previous
//
#include <hip/hip_runtime.h>
#include <hip/hip_bf16.h>

// TriplesDistances: B=16, N=512, A=1024
// positions: float32 [B,N,3]; neighbors_j/k: int32 [B,N,A]; out: float32,
// (r_ij | r_ik | r_jk) each [B,N,A] concatenated flat.
//
// R8 post-mortem: SoA LDS split regressed (+6.4us). Lesson: wave64
// ds_read_b128 has an 8-cyc BW floor (1KB vs 128B/cyc LDS port) regardless
// of banking; conflicts only add ~+4cyc imbalance. LDS is not the lever.
// Component model: HBM 27-30us, VALU 10-12us, LDS 6-8us -> residual ~15us
// of the ~44.5us kernel is unoverlapped stalls at 16 waves/CU.
// R9: revert to float4 spos; halve per-thread state (8 elems/thread, half
// row per wave) so peak regs ~80 -> __launch_bounds__(256,6) = 24 waves/CU
// (+50% TLP) while keeping phase-1 MLP (all index loads in flight).
// Grid 4096 (16 blocks/CU even).

namespace {
constexpr int kB = 16;
constexpr int kN = 512;
constexpr int kA = 1024;
constexpr long long kBNA = (long long)kB * kN * kA;  // 8,388,608

typedef int   iv4 __attribute__((ext_vector_type(4)));
typedef float fv4 __attribute__((ext_vector_type(4)));
}  // namespace

__global__ __launch_bounds__(256, 6) void TriplesDistances_kernel(
    const float* __restrict__ pos,   // f32 [B*N*3]
    const int* __restrict__ nj,      // int32 [B*N*A]
    const int* __restrict__ nk,      // int32 [B*N*A]
    float* __restrict__ out)         // f32 [3*B*N*A]
{
    __shared__ fv4 spos[kN];  // 8 KB, float4-padded positions of this batch

    const int bid = blockIdx.x;        // 0..4095
    const int b   = bid >> 8;          // batch (256 blocks per batch)
    const int n0  = (bid & 255) << 1;  // first of 2 rows
    const int tid = threadIdx.x;

    // Stage batch-b positions: 1536 packed floats -> padded float4 layout.
    {
        const float* p = pos + (size_t)b * (kN * 3);
#pragma unroll
        for (int t = 0; t < 6; ++t) {
            const int e = tid + t * 256;
            const int a = e / 3;         // magic-mul, no HW div
            const int c = e - a * 3;
            ((float*)&spos[a])[c] = p[e];
        }
    }

    const int wave = tid >> 6;          // 0..3
    const int lane = tid & 63;
    const int row  = n0 + (wave >> 1);  // 2 waves per row
    const int half = wave & 1;          // which 512-elem half of the row

    // Wave owns half a row (512 elems); 2 chunks of 256.
    // Thread offset lane*4 => every iv4 load / fv4 store is 1 KB coalesced.
    const long long base = ((long long)b * kN + row) * kA + half * 512;

    // ---- Phase 1: issue all 4 index loads; keep them ALL in flight. ----
    iv4 j4[2], k4[2];
#pragma unroll
    for (int c = 0; c < 2; ++c) {
        const long long off = base + c * 256 + lane * 4;
        j4[c] = *(const iv4*)(nj + off);
        k4[c] = *(const iv4*)(nk + off);
    }

    __syncthreads();                    // spos ready (placed after load issue)
    const fv4 pi = spos[row];
    const float xi = pi.x, yi = pi.y, zi = pi.z;

    // ---- Phase 2: per chunk, batch gathers -> compute -> store. ----
#pragma unroll
    for (int c = 0; c < 2; ++c) {
        const long long off = base + c * 256 + lane * 4;

        const int js[4] = {j4[c].x, j4[c].y, j4[c].z, j4[c].w};
        const int ks[4] = {k4[c].x, k4[c].y, k4[c].z, k4[c].w};

        // Batch all 8 ds_read_b128 gathers before any compute.
        fv4 pj[4], pk[4];
#pragma unroll
        for (int t = 0; t < 4; ++t) {
            pj[t] = spos[js[t]];
            pk[t] = spos[ks[t]];
        }

        fv4 vij, vik, vjk;
        float* rij = (float*)&vij;
        float* rik = (float*)&vik;
        float* rjk = (float*)&vjk;
#pragma unroll
        for (int t = 0; t < 4; ++t) {
            // safe_norm: sqrtf(0)=0 matches where(s>0, sqrt(s), 0)
            float dx = pj[t].x - xi, dy = pj[t].y - yi, dz = pj[t].z - zi;
            rij[t] = sqrtf(dx * dx + dy * dy + dz * dz);

            dx = pk[t].x - xi; dy = pk[t].y - yi; dz = pk[t].z - zi;
            rik[t] = sqrtf(dx * dx + dy * dy + dz * dz);

            dx = pj[t].x - pk[t].x; dy = pj[t].y - pk[t].y; dz = pj[t].z - pk[t].z;
            rjk[t] = sqrtf(dx * dx + dy * dy + dz * dz);
        }

        // 1 KB coalesced plain stores (overwrite poison-dirty L2 lines).
        *(fv4*)(out + off)            = vij;
        *(fv4*)(out + kBNA + off)     = vik;
        *(fv4*)(out + 2 * kBNA + off) = vjk;
    }
}

extern "C" void kernel_launch(void* const* d_in, const int* in_sizes, int n_in,
                              void* d_out, int out_size, void* d_ws, size_t ws_size,
                              hipStream_t stream) {
    const float* pos = (const float*)d_in[0];
    const int* nj = (const int*)d_in[1];
    const int* nk = (const int*)d_in[2];
    float* out = (float*)d_out;

    // 2 rows per block (half-row per wave): grid = B * N/2 = 4096 blocks.
    TriplesDistances_kernel<<<kB * (kN / 2), 256, 0, stream>>>(pos, nj, nk, out);
}

// Round 4
// 153.878 us; speedup vs baseline: 1.0533x; 1.0046x over previous
//
#include <hip/hip_runtime.h>
#include <hip/hip_bf16.h>

// TriplesDistances: B=16, N=512, A=1024
// positions: float32 [B,N,3]; neighbors_j/k: int32 [B,N,A]; out: float32,
// (r_ij | r_ik | r_jk) each [B,N,A] concatenated flat.
//
// R9 post-mortem: +50% TLP gave only -1.1us. TLP/MLP both near-dead levers;
// per-wave serial tail is what moves. Without -ffast-math, sqrtf lowers to
// the IEEE sequence (~10 VALU ops + ~6 temp regs); tolerance (1.5e-2 abs)
// is ~1000x looser than raw v_sqrt_f32 (1 ULP).
// R10: (a) raw v_sqrt_f32 inline asm: -500-700 cyc serial tail per wave,
// frees regs; (b) 4 elems/thread, 1 row/block, grid 8192,
// __launch_bounds__(256,8) -> 32 waves/CU with all index loads in flight.
// Gathers in pairs (16-reg window) to stay under the 64-VGPR cap.

namespace {
constexpr int kB = 16;
constexpr int kN = 512;
constexpr int kA = 1024;
constexpr long long kBNA = (long long)kB * kN * kA;  // 8,388,608

typedef int   iv4 __attribute__((ext_vector_type(4)));
typedef float fv4 __attribute__((ext_vector_type(4)));

__device__ __forceinline__ float fast_sqrt(float s) {
    // absmax tolerance 1.5e-2 >> 1-2 ULP of raw v_sqrt_f32; sqrt(0)=0
    // preserves safe_norm semantics.
    float r;
    asm("v_sqrt_f32 %0, %1" : "=v"(r) : "v"(s));
    return r;
}
}  // namespace

__global__ __launch_bounds__(256, 8) void TriplesDistances_kernel(
    const float* __restrict__ pos,   // f32 [B*N*3]
    const int* __restrict__ nj,      // int32 [B*N*A]
    const int* __restrict__ nk,      // int32 [B*N*A]
    float* __restrict__ out)         // f32 [3*B*N*A]
{
    __shared__ fv4 spos[kN];  // 8 KB, float4-padded positions of this batch

    const int bid = blockIdx.x;        // 0..8191
    const int b   = bid >> 9;          // batch (512 blocks per batch)
    const int row = bid & 511;         // one row per block
    const int tid = threadIdx.x;

    // Stage batch-b positions: 1536 packed floats -> padded float4 layout.
    {
        const float* p = pos + (size_t)b * (kN * 3);
#pragma unroll
        for (int t = 0; t < 6; ++t) {
            const int e = tid + t * 256;
            const int a = e / 3;         // magic-mul, no HW div
            const int c = e - a * 3;
            ((float*)&spos[a])[c] = p[e];
        }
    }

    const int wave = tid >> 6;          // quarter-row per wave
    const int lane = tid & 63;

    // 4 elems/thread; every iv4 load / fv4 store is 1 KB coalesced.
    const long long off = ((long long)b * kN + row) * kA + wave * 256 + lane * 4;

    // Issue both index loads before the barrier; keep them in flight.
    const iv4 j4 = *(const iv4*)(nj + off);
    const iv4 k4 = *(const iv4*)(nk + off);

    __syncthreads();                    // spos ready
    const fv4 pi = spos[row];
    const float xi = pi.x, yi = pi.y, zi = pi.z;

    const int js[4] = {j4.x, j4.y, j4.z, j4.w};
    const int ks[4] = {k4.x, k4.y, k4.z, k4.w};

    fv4 vij, vik, vjk;
    float* rij = (float*)&vij;
    float* rik = (float*)&vik;
    float* rjk = (float*)&vjk;

    // Gather + compute in pairs of points: 4x ds_read_b128 window (16 regs)
    // keeps peak VGPR under the (256,8) 64-reg cap.
#pragma unroll
    for (int p = 0; p < 2; ++p) {
        const fv4 pj0 = spos[js[2 * p + 0]];
        const fv4 pk0 = spos[ks[2 * p + 0]];
        const fv4 pj1 = spos[js[2 * p + 1]];
        const fv4 pk1 = spos[ks[2 * p + 1]];

        float dx = pj0.x - xi, dy = pj0.y - yi, dz = pj0.z - zi;
        rij[2 * p + 0] = fast_sqrt(dx * dx + dy * dy + dz * dz);
        dx = pk0.x - xi; dy = pk0.y - yi; dz = pk0.z - zi;
        rik[2 * p + 0] = fast_sqrt(dx * dx + dy * dy + dz * dz);
        dx = pj0.x - pk0.x; dy = pj0.y - pk0.y; dz = pj0.z - pk0.z;
        rjk[2 * p + 0] = fast_sqrt(dx * dx + dy * dy + dz * dz);

        dx = pj1.x - xi; dy = pj1.y - yi; dz = pj1.z - zi;
        rij[2 * p + 1] = fast_sqrt(dx * dx + dy * dy + dz * dz);
        dx = pk1.x - xi; dy = pk1.y - yi; dz = pk1.z - zi;
        rik[2 * p + 1] = fast_sqrt(dx * dx + dy * dy + dz * dz);
        dx = pj1.x - pk1.x; dy = pj1.y - pk1.y; dz = pj1.z - pk1.z;
        rjk[2 * p + 1] = fast_sqrt(dx * dx + dy * dy + dz * dz);
    }

    // 1 KB coalesced plain stores (overwrite poison-dirty L2 lines).
    *(fv4*)(out + off)            = vij;
    *(fv4*)(out + kBNA + off)     = vik;
    *(fv4*)(out + 2 * kBNA + off) = vjk;
}

extern "C" void kernel_launch(void* const* d_in, const int* in_sizes, int n_in,
                              void* d_out, int out_size, void* d_ws, size_t ws_size,
                              hipStream_t stream) {
    const float* pos = (const float*)d_in[0];
    const int* nj = (const int*)d_in[1];
    const int* nk = (const int*)d_in[2];
    float* out = (float*)d_out;

    // 1 row per block (quarter-row per wave): grid = B * N = 8192 blocks.
    TriplesDistances_kernel<<<kB * kN, 256, 0, stream>>>(pos, nj, nk, out);
}